// Round 7
// baseline (756.595 us; speedup 1.0000x reference)
//
#include <hip/hip_runtime.h>
#include <hip/hip_bf16.h>
#include <math.h>

typedef __bf16 bf16;
typedef __attribute__((ext_vector_type(4))) __bf16 bf16x4;
typedef __attribute__((ext_vector_type(8))) __bf16 bf16x8;
typedef __attribute__((ext_vector_type(4))) float f32x4;

#define GLL(gp, lp) __builtin_amdgcn_global_load_lds( \
    (const __attribute__((address_space(1))) unsigned int*)(gp), \
    (__attribute__((address_space(3))) unsigned int*)(lp), 16, 0, 0)

#define WAIT_LGKM0() do { asm volatile("s_waitcnt lgkmcnt(0)" ::: "memory"); \
                          __builtin_amdgcn_sched_barrier(0); } while (0)
#define WAIT_VMC(n) do { asm volatile("s_waitcnt vmcnt(" #n ")" ::: "memory"); \
                         __builtin_amdgcn_sched_barrier(0); } while (0)
#define BARRIER_FENCE() asm volatile("s_barrier" ::: "memory")

// ---------------------------------------------------------------------------
// Sizes: B=4, H=W=128 (n=16384/batch, 65536 rows total), C=512, HEADS=8, D=64
//
// R6 reformulation: attention scores never need q,k explicitly.
//   G_b = X_b^T X_b (512x512 per batch, bf16 MFMA, fp32 acc)
//   U_b = G_b Wq^T (fp32);  S_b[d,e] = Wk_d . U_b[:,e]   (per head block)
//   ssq[e] = Wq_e . U[:,e];  ssk[d] = Wk_d . (G Wk^T)[:,d]
// Deletes q/k projections (69 GFLOP), q/k HBM round-trip (256MB), attn_dots.
// (R6 bench attempt died on container acquisition, not the kernel; re-audited
// offsets/alignment/zeroing statically and resubmitting unchanged.)
// ---------------------------------------------------------------------------

__device__ __forceinline__ bf16x8 cvt8(float4 a, float4 b) {
  bf16x8 o;
  o[0] = (bf16)a.x; o[1] = (bf16)a.y; o[2] = (bf16)a.z; o[3] = (bf16)a.w;
  o[4] = (bf16)b.x; o[5] = (bf16)b.y; o[6] = (bf16)b.z; o[7] = (bf16)b.w;
  return o;
}

// K0a: x fp32 -> xb (bf16 [n][c] row-major) AND xbT (bf16 [b][c][n]) via
// LDS-tiled 64x64 transpose. grid (ntile 256, ctile 8, b 4).
__global__ __launch_bounds__(256) void prep_x_kernel(
    const float* __restrict__ x, bf16* __restrict__ xb, bf16* __restrict__ xbT)
{
  __shared__ bf16 tr[64 * 72];
  int nt = blockIdx.x, ct = blockIdx.y, b = blockIdx.z;
  int t = threadIdx.x;
  int r = t >> 2, q = (t & 3) * 16;
  const float* xp = x + ((size_t)b << 23) + ((size_t)(nt * 64 + r) << 9) + ct * 64 + q;
  float4 v0 = ((const float4*)xp)[0];
  float4 v1 = ((const float4*)xp)[1];
  float4 v2 = ((const float4*)xp)[2];
  float4 v3 = ((const float4*)xp)[3];
  bf16x8 o0 = cvt8(v0, v1), o1 = cvt8(v2, v3);
  size_t xbo = ((size_t)(b * 16384 + nt * 64 + r) << 9) + ct * 64 + q;
  *(bf16x8*)&xb[xbo] = o0;
  *(bf16x8*)&xb[xbo + 8] = o1;
  bf16 vals[16];
  *(bf16x8*)&vals[0] = o0; *(bf16x8*)&vals[8] = o1;
#pragma unroll
  for (int j = 0; j < 16; ++j) tr[(q + j) * 72 + r] = vals[j];
  __syncthreads();
  int cr = t >> 2, nq = (t & 3) * 16;
  bf16x8 t0 = *(const bf16x8*)&tr[cr * 72 + nq];
  bf16x8 t1 = *(const bf16x8*)&tr[cr * 72 + nq + 8];
  size_t to = ((size_t)b << 23) + ((size_t)(ct * 64 + cr) << 14) + nt * 64 + nq;
  *(bf16x8*)&xbT[to] = t0;
  *(bf16x8*)&xbT[to + 8] = t1;
}

// K0b: Wv fp32 -> bf16; zero G (fp32, split-K atomics) + ssq + ssk.
__global__ __launch_bounds__(256) void prep_w_kernel(
    const float* __restrict__ Wv, bf16* __restrict__ wvb,
    float* __restrict__ G, float* __restrict__ ssq, float* __restrict__ ssk)
{
  const long WVG = 32768;        // 262144/8
  const long GZ  = 262144;       // 4*512*512 floats / 4
  long i = (long)blockIdx.x * 256 + threadIdx.x;
  float4 z = make_float4(0.f, 0.f, 0.f, 0.f);
  if (i < WVG) {
    const float4* sp = (const float4*)Wv;
    float4 a = sp[i * 2], b = sp[i * 2 + 1];
    *(bf16x8*)(wvb + i * 8) = cvt8(a, b);
  } else if (i < WVG + GZ) {
    ((float4*)G)[i - WVG] = z;
  } else if (i < WVG + GZ + 512) {
    ((float4*)ssq)[i - WVG - GZ] = z;
  } else if (i < WVG + GZ + 1024) {
    ((float4*)ssk)[i - WVG - GZ - 512] = z;
  }
}

// ---------------------------------------------------------------------------
// bf16 NT-GEMM mainloop v6 (templated): A (M x K, row stride 2^SHIFT), B
// (N x K same stride), 128x128 tile, BK=32, KITERS iters from kbeg.
// 3-deep LDS pipeline, counted vmcnt; conflict-free swizzle
// slot = kq ^ ((row>>1)&3) on both stage (global side) and read.
// ---------------------------------------------------------------------------
template <int SHIFT, int KITERS>
__device__ __forceinline__ void gemm_tile_mainloop_t(
    const bf16* __restrict__ A, const bf16* __restrict__ B,
    int m0, int n0, int kbeg, bf16* As, bf16* Bs, f32x4 acc[4][4])
{
  int tid = threadIdx.x;
  int lane = tid & 63, wave = tid >> 6;
  int wy = wave >> 1, wx = wave & 1;
  int srow = tid >> 2;                             // 0..63
  int scol = ((tid & 3) ^ ((tid >> 3) & 3)) * 8;   // swizzled global col
  const bf16* ag = A + ((size_t)(m0 + srow) << SHIFT) + kbeg + scol;
  const bf16* bg = B + ((size_t)(n0 + srow) << SHIFT) + kbeg + scol;
  bf16* lA = As + wave * 512;
  bf16* lB = Bs + wave * 512;
  int mloc = lane & 15;
  int kq = lane >> 4;

#define STG(t) do { \
    GLL(ag + (t) * 32,                         lA + ((t) % 3) * 4096);        \
    GLL(ag + (t) * 32 + ((size_t)64 << SHIFT), lA + ((t) % 3) * 4096 + 2048); \
    GLL(bg + (t) * 32,                         lB + ((t) % 3) * 4096);        \
    GLL(bg + (t) * 32 + ((size_t)64 << SHIFT), lB + ((t) % 3) * 4096 + 2048); \
  } while (0)

  STG(0);
  STG(1);
  WAIT_VMC(4);
  BARRIER_FENCE();

#pragma unroll
  for (int t = 0; t < KITERS; ++t) {
    if (t + 2 < KITERS) STG(t + 2);
    const bf16* Ac = As + (t % 3) * 4096;
    const bf16* Bc = Bs + (t % 3) * 4096;
    bf16x8 af[4], bfr[4];
#pragma unroll
    for (int tt = 0; tt < 4; tt++) {
      int arow = wy * 64 + tt * 16 + mloc;
      af[tt] = *(const bf16x8*)&Ac[arow * 32 + ((kq ^ ((arow >> 1) & 3)) << 3)];
      int brow = wx * 64 + tt * 16 + mloc;
      bfr[tt] = *(const bf16x8*)&Bc[brow * 32 + ((kq ^ ((brow >> 1) & 3)) << 3)];
    }
    WAIT_LGKM0();
    __builtin_amdgcn_s_setprio(1);
#pragma unroll
    for (int ty = 0; ty < 4; ty++)
#pragma unroll
      for (int tx = 0; tx < 4; tx++)
        acc[ty][tx] = __builtin_amdgcn_mfma_f32_16x16x32_bf16(
            af[ty], bfr[tx], acc[ty][tx], 0, 0, 0);
    __builtin_amdgcn_s_setprio(0);
    if (t <= KITERS - 3)      { WAIT_VMC(4); }
    else if (t == KITERS - 2) { WAIT_VMC(0); }
    if (t < KITERS - 1) BARRIER_FENCE();
  }
#undef STG
}

// K1: v = (X Wv^T) * illu -> vb bf16 [n][512]. M=65536, N=512, K=512.
// XCD swizzle: 4 nt-siblings of an mt share one XCD (A panel L2-hot).
__global__ __launch_bounds__(256, 3) void gemm_v_kernel(
    const bf16* __restrict__ xb, const bf16* __restrict__ wvb,
    const float* __restrict__ illu, bf16* __restrict__ vb)
{
  __shared__ __align__(16) bf16 As[12288];
  __shared__ __align__(16) bf16 Bs[12288];
  int bid = blockIdx.x;
  int xcd = bid & 7, s = bid >> 3;          // s in [0,256)
  int mt = xcd * 64 + (s >> 2), nt = s & 3;
  int m0 = mt * 128, n0 = nt * 128;
  f32x4 acc[4][4] = {};
  gemm_tile_mainloop_t<9, 16>(xb, wvb, m0, n0, 0, As, Bs, acc);

  int tid = threadIdx.x, lane = tid & 63, wave = tid >> 6;
  int wy = wave >> 1, wx = wave & 1;
  int r0 = m0 + wy * 64 + ((lane >> 4) << 2);
  int c0 = n0 + wx * 64 + (lane & 15);
#pragma unroll
  for (int tx = 0; tx < 4; tx++) {
    int lc = c0 + tx * 16;
#pragma unroll
    for (int ty = 0; ty < 4; ty++) {
#pragma unroll
      for (int r = 0; r < 4; r++) {
        size_t idx = ((size_t)(r0 + ty * 16 + r) << 9) + lc;
        vb[idx] = (bf16)(acc[ty][tx][r] * illu[idx]);
      }
    }
  }
}

// K2: G_b = X_b^T X_b. A=B=xbT_b (512 x 16384, stride 2^14). Split-K=8,
// fp32 atomicAdd partials into pre-zeroed G. grid (tile 16, ks 8, b 4).
__global__ __launch_bounds__(256, 3) void gemm_g_kernel(
    const bf16* __restrict__ xbT, float* __restrict__ G)
{
  __shared__ __align__(16) bf16 As[12288];
  __shared__ __align__(16) bf16 Bs[12288];
  int tile = blockIdx.x, ks = blockIdx.y, b = blockIdx.z;
  int mt = tile >> 2, nt = tile & 3;
  const bf16* Ab = xbT + ((size_t)b << 23);
  f32x4 acc[4][4] = {};
  gemm_tile_mainloop_t<14, 64>(Ab, Ab, mt * 128, nt * 128, ks * 2048, As, Bs, acc);

  float* gp = G + b * 262144;
  int tid = threadIdx.x, lane = tid & 63, wave = tid >> 6;
  int wy = wave >> 1, wx = wave & 1;
  int r0 = mt * 128 + wy * 64 + ((lane >> 4) << 2);
  int c0 = nt * 128 + wx * 64 + (lane & 15);
#pragma unroll
  for (int ty = 0; ty < 4; ty++)
#pragma unroll
    for (int tx = 0; tx < 4; tx++)
#pragma unroll
      for (int r = 0; r < 4; r++)
        atomicAdd(&gp[(r0 + ty * 16 + r) * 512 + c0 + tx * 16], acc[ty][tx][r]);
}

// K3: U_b[c][e] = sum_c' G_b[c][c'] W[e][c']  (W = Wq for uv=0 -> store U;
// W = Wk for uv=1 -> discard). Fused diag partials:
// ssq[e] += sum_c Wq[e,c] U[c,e] (uv=0);  ssk likewise (uv=1).
// fp32 VALU; 64x64 out tile; grid (tile 64, uv 2, b 4).
__global__ __launch_bounds__(256) void small1_kernel(
    const float* __restrict__ G, const float* __restrict__ Wq,
    const float* __restrict__ Wk, float* __restrict__ U,
    float* __restrict__ ssq, float* __restrict__ ssk)
{
  __shared__ float Gs[64 * 68];   // [k=c'][c]   (transposed store)
  __shared__ float Ws[64 * 68];   // [k=c'][e]   (transposed store)
  int tile = blockIdx.x, uv = blockIdx.y, b = blockIdx.z;
  const float* W = uv ? Wk : Wq;
  const float* Gb = G + b * 262144;
  int c0 = (tile >> 3) * 64, e0 = (tile & 7) * 64;
  int t = threadIdx.x;
  int r = t >> 2, q = (t & 3) * 16;
  int cl = (t & 15) * 4, el = (t >> 4) * 4;
  float acc[4][4] = {};
  for (int kc = 0; kc < 512; kc += 64) {
    __syncthreads();
    float g[16], w[16];
    const float* gsrc = &Gb[(size_t)(c0 + r) * 512 + kc + q];
    const float* wsrc = &W[(size_t)(e0 + r) * 512 + kc + q];
#pragma unroll
    for (int j = 0; j < 4; ++j) {
      *(float4*)&g[j * 4] = ((const float4*)gsrc)[j];
      *(float4*)&w[j * 4] = ((const float4*)wsrc)[j];
    }
#pragma unroll
    for (int j = 0; j < 16; ++j) {
      Gs[(q + j) * 68 + r] = g[j];
      Ws[(q + j) * 68 + r] = w[j];
    }
    __syncthreads();
#pragma unroll 8
    for (int k = 0; k < 64; ++k) {
      float4 gv = *(const float4*)&Gs[k * 68 + cl];
      float4 wv = *(const float4*)&Ws[k * 68 + el];
      acc[0][0] += gv.x * wv.x; acc[0][1] += gv.x * wv.y; acc[0][2] += gv.x * wv.z; acc[0][3] += gv.x * wv.w;
      acc[1][0] += gv.y * wv.x; acc[1][1] += gv.y * wv.y; acc[1][2] += gv.y * wv.z; acc[1][3] += gv.y * wv.w;
      acc[2][0] += gv.z * wv.x; acc[2][1] += gv.z * wv.y; acc[2][2] += gv.z * wv.z; acc[2][3] += gv.z * wv.w;
      acc[3][0] += gv.w * wv.x; acc[3][1] += gv.w * wv.y; acc[3][2] += gv.w * wv.z; acc[3][3] += gv.w * wv.w;
    }
  }
  if (uv == 0) {
    float* Ub = U + b * 262144;
#pragma unroll
    for (int i = 0; i < 4; ++i)
      *(float4*)&Ub[(size_t)(c0 + cl + i) * 512 + e0 + el] =
          make_float4(acc[i][0], acc[i][1], acc[i][2], acc[i][3]);
  }
  float* ss = (uv ? ssk : ssq) + b * 512;
#pragma unroll
  for (int j = 0; j < 4; ++j) {
    float p = 0.f;
#pragma unroll
    for (int i = 0; i < 4; ++i)
      p += acc[i][j] * W[(size_t)(e0 + el + j) * 512 + c0 + cl + i];
    p += __shfl_xor(p, 1);
    p += __shfl_xor(p, 2);
    p += __shfl_xor(p, 4);
    p += __shfl_xor(p, 8);
    if ((t & 15) == 0) atomicAdd(&ss[e0 + el + j], p);
  }
}

// K4: S_h[d][e] = sum_c Wk[h*64+d, c] U_b[c, h*64+e]; then
// logits = S * rescale[h] / (nk[d] nq[e]); softmax over e -> attn fp32.
// grid (h 8, b 4).
__global__ __launch_bounds__(256) void small2_kernel(
    const float* __restrict__ U, const float* __restrict__ Wk,
    const float* __restrict__ ssq, const float* __restrict__ ssk,
    const float* __restrict__ rescale, float* __restrict__ attn)
{
  __shared__ float Wks[64 * 68];   // [k=c][d] (transposed store)
  __shared__ float Us[64 * 68];    // [k=c][e]
  __shared__ float att[64 * 65];
  int h = blockIdx.x, b = blockIdx.y;
  const float* Ub = U + b * 262144;
  int t = threadIdx.x;
  int r = t >> 2, q = (t & 3) * 16;
  int dl = (t & 15) * 4, el = (t >> 4) * 4;
  float acc[4][4] = {};
  for (int kc = 0; kc < 512; kc += 64) {
    __syncthreads();
    float wk[16], uu[16];
    const float* wsrc = &Wk[(size_t)(h * 64 + r) * 512 + kc + q];
    const float* usrc = &Ub[(size_t)(kc + r) * 512 + h * 64 + q];
#pragma unroll
    for (int j = 0; j < 4; ++j) {
      *(float4*)&wk[j * 4] = ((const float4*)wsrc)[j];
      *(float4*)&uu[j * 4] = ((const float4*)usrc)[j];
    }
#pragma unroll
    for (int j = 0; j < 16; ++j) Wks[(q + j) * 68 + r] = wk[j];
    // Us rows are already k: direct store
#pragma unroll
    for (int j = 0; j < 4; ++j)
      *(float4*)&Us[r * 68 + q + j * 4] = *(const float4*)&uu[j * 4];
    __syncthreads();
#pragma unroll 8
    for (int k = 0; k < 64; ++k) {
      float4 wv = *(const float4*)&Wks[k * 68 + dl];
      float4 uv = *(const float4*)&Us[k * 68 + el];
      acc[0][0] += wv.x * uv.x; acc[0][1] += wv.x * uv.y; acc[0][2] += wv.x * uv.z; acc[0][3] += wv.x * uv.w;
      acc[1][0] += wv.y * uv.x; acc[1][1] += wv.y * uv.y; acc[1][2] += wv.y * uv.z; acc[1][3] += wv.y * uv.w;
      acc[2][0] += wv.z * uv.x; acc[2][1] += wv.z * uv.y; acc[2][2] += wv.z * uv.z; acc[2][3] += wv.z * uv.w;
      acc[3][0] += wv.w * uv.x; acc[3][1] += wv.w * uv.y; acc[3][2] += wv.w * uv.z; acc[3][3] += wv.w * uv.w;
    }
  }
  float rs = rescale[h];
  float nqv[4], nkv[4];
#pragma unroll
  for (int j = 0; j < 4; ++j)
    nqv[j] = fmaxf(sqrtf(ssq[b * 512 + h * 64 + el + j]), 1e-12f);
#pragma unroll
  for (int i = 0; i < 4; ++i)
    nkv[i] = fmaxf(sqrtf(ssk[b * 512 + h * 64 + dl + i]), 1e-12f);
#pragma unroll
  for (int i = 0; i < 4; ++i)
#pragma unroll
    for (int j = 0; j < 4; ++j)
      att[(dl + i) * 65 + el + j] = acc[i][j] * rs / (nkv[i] * nqv[j]);
  __syncthreads();
  if (t < 64) {
    float m = -3.4e38f;
    for (int e = 0; e < 64; ++e) m = fmaxf(m, att[t * 65 + e]);
    float s = 0.f;
    for (int e = 0; e < 64; ++e) {
      float ex = expf(att[t * 65 + e] - m);
      s += ex;
      att[t * 65 + e] = ex;
    }
    float* ap = attn + (((size_t)(b * 8 + h)) << 12) + t * 64;
    for (int e = 0; e < 64; ++e) ap[e] = att[t * 65 + e] / s;
  }
}

// K5: W_effT[b][co][h*64+e] = sum_d attn[b,h,d,e] * Wp[co, h*64+d]  (bf16).
__global__ __launch_bounds__(256) void weff_kernel(
    const float* __restrict__ attn, const float* __restrict__ Wp,
    bf16* __restrict__ wefT)
{
  int cog = blockIdx.x, h = blockIdx.y, b = blockIdx.z;
  __shared__ float at[4096];   // [d][e]
  __shared__ float wp[4096];   // [co_l][d]
  int t = threadIdx.x;
  const float* ap = attn + ((size_t)(b * 8 + h) << 12);
  for (int i = t; i < 4096; i += 256) at[i] = ap[i];
  for (int i = t; i < 4096; i += 256) {
    int r = i >> 6, d = i & 63;
    wp[i] = Wp[((size_t)(cog * 64 + r) << 9) + h * 64 + d];
  }
  __syncthreads();
  int co_l = (t & 15) * 4, e_l = (t >> 4) * 4;
  float acc[16] = {0};
  for (int d = 0; d < 64; d++) {
    float w0 = wp[(co_l + 0) * 64 + d];
    float w1 = wp[(co_l + 1) * 64 + d];
    float w2 = wp[(co_l + 2) * 64 + d];
    float w3 = wp[(co_l + 3) * 64 + d];
    float4 av = *(const float4*)&at[d * 64 + e_l];
    acc[0]  += w0 * av.x; acc[1]  += w0 * av.y; acc[2]  += w0 * av.z; acc[3]  += w0 * av.w;
    acc[4]  += w1 * av.x; acc[5]  += w1 * av.y; acc[6]  += w1 * av.z; acc[7]  += w1 * av.w;
    acc[8]  += w2 * av.x; acc[9]  += w2 * av.y; acc[10] += w2 * av.z; acc[11] += w2 * av.w;
    acc[12] += w3 * av.x; acc[13] += w3 * av.y; acc[14] += w3 * av.z; acc[15] += w3 * av.w;
  }
#pragma unroll
  for (int i = 0; i < 4; i++)
#pragma unroll
    for (int j = 0; j < 4; j++)
      wefT[((size_t)b << 18) + ((size_t)(cog * 64 + co_l + i) << 9) + h * 64 + e_l + j] =
          (bf16)acc[i * 4 + j];
}

// K6: out_c = v @ W_eff[b] + bp  -> d_out (fp32).
__global__ __launch_bounds__(256, 3) void gemm_out_kernel(
    const bf16* __restrict__ vb, const bf16* __restrict__ wefT,
    const float* __restrict__ bp, float* __restrict__ out)
{
  __shared__ __align__(16) bf16 As[12288];
  __shared__ __align__(16) bf16 Bs[12288];
  int b = blockIdx.y;
  int bid = blockIdx.x;
  int xcd = bid & 7, s = bid >> 3;          // s in [0,64)
  int mt = xcd * 16 + (s >> 2), nt = s & 3;
  int m0 = mt * 128, n0 = nt * 128;
  const bf16* A = vb + ((size_t)b << 23);
  const bf16* B = wefT + ((size_t)b << 18);
  f32x4 acc[4][4] = {};
  gemm_tile_mainloop_t<9, 16>(A, B, m0, n0, 0, As, Bs, acc);

  int tid = threadIdx.x, lane = tid & 63, wave = tid >> 6;
  int wy = wave >> 1, wx = wave & 1;
  int r0 = (b << 14) + m0 + wy * 64 + ((lane >> 4) << 2);
  int c0 = n0 + wx * 64 + (lane & 15);
#pragma unroll
  for (int ty = 0; ty < 4; ty++) {
#pragma unroll
    for (int tx = 0; tx < 4; tx++) {
      int lc = c0 + tx * 16;
      float bias = bp[lc];
#pragma unroll
      for (int r = 0; r < 4; r++) {
        int grow = r0 + ty * 16 + r;
        out[((size_t)grow << 9) + lc] = acc[ty][tx][r] + bias;
      }
    }
  }
}

// K7 (fused conv1+conv2): per block, 8x8 output tile x 128-channel slice.
// Phase 1: p = gelu_erf(dwconv3x3(v, pe1)) on the 10x10 halo -> LDS.
// Phase 2: out += dwconv3x3(p, pe2) (fp32 RMW).
__global__ __launch_bounds__(256) void conv_fused_kernel(
    const bf16* __restrict__ vb, const float* __restrict__ pe1,
    const float* __restrict__ pe2, float* __restrict__ out)
{
  __shared__ __align__(16) bf16 ps[10 * 10 * 128];
  int b = blockIdx.z;
  int cs = blockIdx.y;
  int tile = blockIdx.x;
  int y0 = (tile >> 4) * 8, x0 = (tile & 15) * 8;
  int t = threadIdx.x;
  int cl = (t & 15) * 8;
  int cg = cs * 128 + cl;
  int sp = t >> 4;
  const bf16* vbase = vb + ((size_t)b << 23);

  {
    float w1[72];
#pragma unroll
    for (int i = 0; i < 8; i++)
#pragma unroll
      for (int k = 0; k < 9; k++)
        w1[i * 9 + k] = pe1[(cg + i) * 9 + k];
    for (int pos = sp; pos < 100; pos += 16) {
      int py = pos / 10, px = pos % 10;
      int yy = y0 - 1 + py, xx = x0 - 1 + px;
      bf16x8 o;
      if (yy >= 0 && yy < 128 && xx >= 0 && xx < 128) {
        float a[8] = {0, 0, 0, 0, 0, 0, 0, 0};
#pragma unroll
        for (int ky = 0; ky < 3; ky++) {
          int sy = yy + ky - 1;
          if (sy < 0 || sy >= 128) continue;
#pragma unroll
          for (int kx = 0; kx < 3; kx++) {
            int sx = xx + kx - 1;
            if (sx < 0 || sx >= 128) continue;
            bf16x8 vv = *(const bf16x8*)&vbase[((size_t)(sy * 128 + sx) << 9) + cg];
#pragma unroll
            for (int i = 0; i < 8; i++) a[i] += (float)vv[i] * w1[i * 9 + ky * 3 + kx];
          }
        }
#pragma unroll
        for (int i = 0; i < 8; i++) {
          float g = 0.5f * a[i] * (1.0f + erff(a[i] * 0.70710678118654752f));
          o[i] = (bf16)g;
        }
      } else {
#pragma unroll
        for (int i = 0; i < 8; i++) o[i] = (bf16)0.0f;
      }
      *(bf16x8*)&ps[(py * 10 + px) * 128 + cl] = o;
    }
  }
  __syncthreads();

  float w2[72];
#pragma unroll
  for (int i = 0; i < 8; i++)
#pragma unroll
    for (int k = 0; k < 9; k++)
      w2[i * 9 + k] = pe2[(cg + i) * 9 + k];
  float* ob = out + ((size_t)b << 23);
  for (int o = sp; o < 64; o += 16) {
    int oy = o >> 3, ox = o & 7;
    float a[8] = {0, 0, 0, 0, 0, 0, 0, 0};
#pragma unroll
    for (int ky = 0; ky < 3; ky++)
#pragma unroll
      for (int kx = 0; kx < 3; kx++) {
        bf16x8 pv = *(const bf16x8*)&ps[((oy + ky) * 10 + (ox + kx)) * 128 + cl];
#pragma unroll
        for (int i = 0; i < 8; i++) a[i] += (float)pv[i] * w2[i * 9 + ky * 3 + kx];
      }
    size_t oi = ((size_t)((y0 + oy) * 128 + (x0 + ox)) << 9) + cg;
    float4 o0 = *(float4*)&ob[oi];
    float4 o1 = *(float4*)&ob[oi + 4];
    o0.x += a[0]; o0.y += a[1]; o0.z += a[2]; o0.w += a[3];
    o1.x += a[4]; o1.y += a[5]; o1.z += a[6]; o1.w += a[7];
    *(float4*)&ob[oi] = o0;
    *(float4*)&ob[oi + 4] = o1;
  }
}

extern "C" void kernel_launch(void* const* d_in, const int* in_sizes, int n_in,
                              void* d_out, int out_size, void* d_ws, size_t ws_size,
                              hipStream_t stream) {
  (void)in_sizes; (void)n_in; (void)out_size; (void)ws_size;
  const float* x       = (const float*)d_in[0];
  const float* illu    = (const float*)d_in[1];
  const float* Wq      = (const float*)d_in[2];
  const float* Wk      = (const float*)d_in[3];
  const float* Wv      = (const float*)d_in[4];
  const float* rescale = (const float*)d_in[5];
  const float* Wp      = (const float*)d_in[6];
  const float* bp      = (const float*)d_in[7];
  const float* pe1     = (const float*)d_in[8];
  const float* pe2     = (const float*)d_in[9];
  float* out = (float*)d_out;
  char* ws = (char*)d_ws;

  // workspace layout (bytes); total = 212,877,312
  bf16*  xb   = (bf16*)(ws);                      // 67,108,864  [n][c]
  bf16*  xbT  = (bf16*)(ws + 67108864);           // 67,108,864  [b][c][n]
  bf16*  vb   = (bf16*)(ws + 134217728);          // 67,108,864  [n][c]
  bf16*  wvb  = (bf16*)(ws + 201326592);          //    524,288
  float* G    = (float*)(ws + 201850880);         //  4,194,304  [b][c][c']
  float* U    = (float*)(ws + 206045184);         //  4,194,304  [b][c][e]
  float* ssq  = (float*)(ws + 210239488);         //      8,192
  float* ssk  = (float*)(ws + 210247680);         //      8,192
  float* attn = (float*)(ws + 210255872);         //    524,288
  bf16*  wefT = (bf16*)(ws + 210780160);          //  2,097,152

  prep_x_kernel<<<dim3(256, 8, 4), 256, 0, stream>>>(x, xb, xbT);
  prep_w_kernel<<<1156, 256, 0, stream>>>(Wv, wvb, G, ssq, ssk);
  gemm_v_kernel<<<2048, 256, 0, stream>>>(xb, wvb, illu, vb);
  gemm_g_kernel<<<dim3(16, 8, 4), 256, 0, stream>>>(xbT, G);
  small1_kernel<<<dim3(64, 2, 4), 256, 0, stream>>>(G, Wq, Wk, U, ssq, ssk);
  small2_kernel<<<dim3(8, 4), 256, 0, stream>>>(U, Wk, ssq, ssk, rescale, attn);
  weff_kernel<<<dim3(8, 8, 4), 256, 0, stream>>>(attn, Wp, wefT);
  gemm_out_kernel<<<dim3(512, 4), 256, 0, stream>>>(vb, wefT, bp, out);
  conv_fused_kernel<<<dim3(256, 4, 4), 256, 0, stream>>>(vb, pe1, pe2, out);
}